// Round 20
// baseline (230.323 us; speedup 1.0000x reference)
//
#include <hip/hip_runtime.h>

namespace {
constexpr int NA = 8, BT = 32768, NOBS = 64, NACT = 16, NH = 128;
constexpr int TOK = 16, NTHREADS = 512;
// g_wt table offsets (u16 units)
constexpr int OFF_ENC = 0;        // [8][128n][96k] (k>=80 zero)
constexpr int OFF_S   = 98304;    // [8][128n][64k]
constexpr int OFF_KEY = 163840;   // [128n][128k]  n = e*32+d
constexpr int OFF_SEL = 180224;   // [128n][128k]
constexpr int OFF_VAL = 196608;   // [128n][128k]
constexpr int OFF_C1  = 212992;   // [8][128n][256k]
constexpr int OFF_C2  = 475136;   // [8][16n][128k]
constexpr int WT_TOTAL = 491520;
// enc LDS (u16): WENC [128][104] (96 used), WS_ [128][72] (64 used), SCR 8x640
constexpr int WENC = 0, WS_ = 13312, ESCR = 22528, ENC_LDS = 27648;   // 55,296 B
// attn LDS (u16), per-head-pass slices: WK2/WS2 [64n][128] swizzled, KOFF2/SOFF2 [256][40]
// 40-pad rows: cols 0-31 data, cols 32-39 spare (logit scratch); KOFF2 cols 0-15 hold w
// (f32) after keys die at B2. Total 73,728 B -> 2 blocks/CU.
constexpr int WK2 = 0, WS2 = 8192, KOFF2 = 16384, SOFF2 = 26624, ATTN_LDS = 36864;
}

typedef short short8 __attribute__((ext_vector_type(8)));
typedef float f32x4 __attribute__((ext_vector_type(4)));
typedef unsigned short u16;

__device__ u16 g_wt[WT_TOTAL];
__device__ u16 g_sa[(size_t)NA * BT * NH];       // [a][t][128] sa-encodings
__device__ u16 g_ci[(size_t)NA * BT * 2 * NH];   // [a][t][256]: 0-127 se, 128-255 other

__device__ __forceinline__ u16 f2b(float x) {  // RNE f32->bf16
  unsigned b = __float_as_uint(x);
  return (u16)((b + 0x7FFFu + ((b >> 16) & 1u)) >> 16);
}
__device__ __forceinline__ float b2f(u16 h) { return __uint_as_float(((unsigned)h) << 16); }
__device__ __forceinline__ float lrelu(float x) { return x > 0.0f ? x : 0.01f * x; }
__device__ __forceinline__ short8 ld8(const u16* p) { return *reinterpret_cast<const short8*>(p); }
__device__ __forceinline__ void st8(u16* p, short8 v) { *reinterpret_cast<short8*>(p) = v; }
__device__ __forceinline__ short8 pk8(float4 p, float4 q) {
  short8 r;
  r[0] = (short)f2b(p.x); r[1] = (short)f2b(p.y); r[2] = (short)f2b(p.z); r[3] = (short)f2b(p.w);
  r[4] = (short)f2b(q.x); r[5] = (short)f2b(q.y); r[6] = (short)f2b(q.z); r[7] = (short)f2b(q.w);
  return r;
}

// ---------------- K0: transpose+cvt all weights into g_wt ----------------
__global__ void maac_wt(const float* __restrict__ encW, const float* __restrict__ sW,
                        const float* __restrict__ keyW, const float* __restrict__ selW,
                        const float* __restrict__ valW, const float* __restrict__ cW1,
                        const float* __restrict__ cW2) {
  for (int i = blockIdx.x * blockDim.x + threadIdx.x; i < WT_TOTAL; i += gridDim.x * blockDim.x) {
    float v; int o = i;
    if (o < OFF_S) {                // enc: [a][n][96] <- encW[a][k][n], zero k>=80
      int a = o / 12288, r = o % 12288, n = r / 96, k = r % 96;
      v = (k < 80) ? encW[a * 10240 + k * 128 + n] : 0.0f;
    } else if (o < OFF_KEY) {       // s: [a][n][64]
      int q = o - OFF_S; int a = q / 8192, r = q % 8192, n = r / 64, k = r % 64;
      v = sW[a * 8192 + k * 128 + n];
    } else if (o < OFF_SEL) {       // key: [n=e*32+d][k=h]
      int q = o - OFF_KEY; int n = q / 128, k = q % 128;
      v = keyW[(n >> 5) * 4096 + k * 32 + (n & 31)];
    } else if (o < OFF_VAL) {
      int q = o - OFF_SEL; int n = q / 128, k = q % 128;
      v = selW[(n >> 5) * 4096 + k * 32 + (n & 31)];
    } else if (o < OFF_C1) {
      int q = o - OFF_VAL; int n = q / 128, k = q % 128;
      v = valW[(n >> 5) * 4096 + k * 32 + (n & 31)];
    } else if (o < OFF_C2) {        // c1: [a][n][256]
      int q = o - OFF_C1; int a = q / 32768, r = q % 32768, n = r / 256, k = r % 256;
      v = cW1[a * 32768 + k * 128 + n];
    } else {                        // c2: [a][n=o][128]
      int q = o - OFF_C2; int a = q / 2048, r = q % 2048, n = r / 128, k = r % 128;
      v = cW2[a * 2048 + k * 16 + n];
    }
    g_wt[i] = f2b(v);
  }
}

// ---------------- K1: enc + s_enc, crit-pattern: per-agent 128-token blocks ----------------
__global__ __launch_bounds__(NTHREADS) __attribute__((amdgpu_waves_per_eu(4)))
void maac_enc(const float* __restrict__ g_obs, const float* __restrict__ g_u,
              const float* __restrict__ g_encb, const float* __restrict__ g_sb) {
  __shared__ __align__(16) u16 lds[ENC_LDS];

  const int tid = threadIdx.x;
  const int a = blockIdx.y;
  const int tok0 = blockIdx.x * 128;

  // stage encW[a] rows(96) -> 104-pad; sW[a] rows(64) -> 72-pad (both <=2-way banks)
  for (int z = tid * 8; z < 12288; z += NTHREADS * 8) {
    int row = z / 96, k = z - row * 96;
    st8(&lds[WENC + row * 104 + k], ld8(&g_wt[OFF_ENC + a * 12288 + z]));
  }
  for (int z = tid * 8; z < 8192; z += NTHREADS * 8) {
    int row = z >> 6, k = z & 63;
    st8(&lds[WS_ + row * 72 + k], ld8(&g_wt[OFF_S + a * 8192 + z]));
  }
  __syncthreads();

  const int wv = tid >> 6, l = tid & 63, lr = l & 15, lg = l >> 4;
  const int g0 = tok0 + wv * 16;
  const int scrw = ESCR + wv * 640;

  // A-frags: row = token g0+lr, k = ks*32+lg*8+j
  short8 afr0, afr1, afr2;
  {
    const float4* o4 = reinterpret_cast<const float4*>(g_obs + ((size_t)a * BT + g0 + lr) * NOBS);
    afr0 = pk8(o4[lg * 2], o4[lg * 2 + 1]);
    afr1 = pk8(o4[8 + lg * 2], o4[8 + lg * 2 + 1]);
    if (lg < 2) {
      const float4* u4 = reinterpret_cast<const float4*>(g_u + ((size_t)a * BT + g0 + lr) * NACT);
      afr2 = pk8(u4[lg * 2], u4[lg * 2 + 1]);
    } else {
      afr2 = short8{0, 0, 0, 0, 0, 0, 0, 0};
    }
  }

  // P1: sa = lrelu(inp @ encW + encb) -> granule roundtrip -> g_sa
  #pragma unroll
  for (int g = 0; g < 4; ++g) {
    #pragma unroll
    for (int ntl = 0; ntl < 2; ++ntl) {
      const int nt = 2 * g + ntl;
      f32x4 acc = {0.f, 0.f, 0.f, 0.f};
      const u16* wr = &lds[WENC + (nt * 16 + lr) * 104 + lg * 8];
      acc = __builtin_amdgcn_mfma_f32_16x16x32_bf16(afr0, ld8(wr), acc, 0, 0, 0);
      acc = __builtin_amdgcn_mfma_f32_16x16x32_bf16(afr1, ld8(wr + 32), acc, 0, 0, 0);
      acc = __builtin_amdgcn_mfma_f32_16x16x32_bf16(afr2, ld8(wr + 64), acc, 0, 0, 0);
      float bias = g_encb[a * NH + nt * 16 + lr];
      #pragma unroll
      for (int r = 0; r < 4; ++r)
        lds[scrw + (4 * lg + r) * 40 + ntl * 16 + lr] = f2b(lrelu(acc[r] + bias));
    }
    st8(&g_sa[((size_t)a * BT + g0 + lr) * NH + g * 32 + lg * 8],
        ld8(&lds[scrw + lr * 40 + lg * 8]));   // wave-private, DS-ordered
  }
  // P2: se = lrelu(obs @ sW + sb) -> g_ci cols 0..127
  #pragma unroll
  for (int g = 0; g < 4; ++g) {
    #pragma unroll
    for (int ntl = 0; ntl < 2; ++ntl) {
      const int nt = 2 * g + ntl;
      f32x4 acc = {0.f, 0.f, 0.f, 0.f};
      const u16* wr = &lds[WS_ + (nt * 16 + lr) * 72 + lg * 8];
      acc = __builtin_amdgcn_mfma_f32_16x16x32_bf16(afr0, ld8(wr), acc, 0, 0, 0);
      acc = __builtin_amdgcn_mfma_f32_16x16x32_bf16(afr1, ld8(wr + 32), acc, 0, 0, 0);
      float bias = g_sb[a * NH + nt * 16 + lr];
      #pragma unroll
      for (int r = 0; r < 4; ++r)
        lds[scrw + (4 * lg + r) * 40 + ntl * 16 + lr] = f2b(lrelu(acc[r] + bias));
    }
    st8(&g_ci[((size_t)a * BT + g0 + lr) * 256 + g * 32 + lg * 8],
        ld8(&lds[scrw + lr * 40 + lg * 8]));
  }
}

// ---------------- K2: attention, two head-passes; P5/P7 on ALL 512 threads ----------------
// r18/r19 structure; P5 split into P5a (512 thr, 4 logits each, scratch = spare cols
// 32..39 of the 40-pad rows) + P5b (256 thr softmax, w stored f32 into dead KOFF2 keys).
// P7 split 2-q-per-thread across 512. FP order per output identical to r17/r18.
__global__ __launch_bounds__(NTHREADS) __attribute__((amdgpu_waves_per_eu(4)))
void maac_attn(const float* __restrict__ g_valb) {
  __shared__ __align__(16) u16 lds[ATTN_LDS];

  const int tid = threadIdx.x;
  const int g0 = blockIdx.x * TOK;
  const int a = tid >> 6, l = tid & 63, lr = l & 15, lg = l >> 4;

  // sa/se fragments from global (one-time)
  short8 safr[4], sefr[4];
  #pragma unroll
  for (int ks = 0; ks < 4; ++ks) {
    safr[ks] = ld8(&g_sa[((size_t)a * BT + g0 + lr) * NH + ks * 32 + lg * 8]);
    sefr[ks] = ld8(&g_ci[((size_t)a * BT + g0 + lr) * 256 + ks * 32 + lg * 8]);
  }

  for (int ep = 0; ep < 2; ++ep) {
    // ---- stage key/sel slices for heads {2ep, 2ep+1}: rows ep*64..+63, col-swizzled ----
    for (int z = tid * 8; z < 8192; z += NTHREADS * 8) {
      int rl = z >> 7, c = z & 127;
      int cs = c ^ ((rl & 7) * 8);
      st8(&lds[WK2 + rl * 128 + cs], ld8(&g_wt[OFF_KEY + ep * 8192 + z]));
      st8(&lds[WS2 + rl * 128 + cs], ld8(&g_wt[OFF_SEL + ep * 8192 + z]));
    }
    __syncthreads();   // B0: slices staged (orders vs prev pass's P7 SOFF2 reads)

    // ---- P3: keys -> KOFF2 ; sel -> SOFF2 (B from LDS, swizzled) ----
    #pragma unroll
    for (int ntL = 0; ntL < 4; ++ntL) {
      const int eh = ntL >> 1, ntl = ntL & 1;
      const int d = ntl * 16 + lr;
      const int rl = eh * 32 + d;                 // local weight row
      const int swz = (lr & 7) * 8;
      const u16* wk = &lds[WK2 + rl * 128];
      const u16* ws = &lds[WS2 + rl * 128];
      f32x4 ak = {0.f, 0.f, 0.f, 0.f}, as_ = {0.f, 0.f, 0.f, 0.f};
      #pragma unroll
      for (int ks = 0; ks < 4; ++ks) {
        const int col = (ks * 32 + lg * 8) ^ swz;
        ak  = __builtin_amdgcn_mfma_f32_16x16x32_bf16(safr[ks], ld8(wk + col), ak, 0, 0, 0);
        as_ = __builtin_amdgcn_mfma_f32_16x16x32_bf16(sefr[ks], ld8(ws + col), as_, 0, 0, 0);
      }
      #pragma unroll
      for (int r = 0; r < 4; ++r) {
        const int row = (eh * 8 + a) * 16 + 4 * lg + r;
        lds[KOFF2 + row * 40 + d] = f2b(ak[r]);
        lds[SOFF2 + row * 40 + d] = f2b(as_[r]);
      }
    }
    __syncthreads();   // B1: keys+sel visible; WK2/WS2 now dead

    // ---- val-slice staging into WK2 (overlaps with P5a; no region conflict) ----
    for (int z = tid * 8; z < 8192; z += NTHREADS * 8) {
      int rl = z >> 7, c = z & 127;
      int cs = c ^ ((rl & 7) * 8);
      st8(&lds[WK2 + rl * 128 + cs], ld8(&g_wt[OFF_VAL + ep * 8192 + z]));
    }

    // ---- P5a: logits on ALL 512 threads: thread = (jh,eh,i,t), 4 logits each ----
    {
      const int jh = tid >> 8, eh = (tid >> 7) & 1, i = (tid >> 4) & 7, t = tid & 15;
      const int rit = (eh * 8 + i) * 16 + t;
      const int j0 = jh * 4;
      float a0 = 0.f, a1 = 0.f, a2 = 0.f, a3 = 0.f;
      #pragma unroll
      for (int q = 0; q < 4; ++q) {
        short8 s = ld8(&lds[SOFF2 + rit * 40 + q * 8]);
        float sel8[8];
        #pragma unroll
        for (int z = 0; z < 8; ++z) sel8[z] = b2f((u16)s[z]);
        short8 k0 = ld8(&lds[KOFF2 + ((eh * 8 + j0 + 0) * 16 + t) * 40 + q * 8]);
        short8 k1 = ld8(&lds[KOFF2 + ((eh * 8 + j0 + 1) * 16 + t) * 40 + q * 8]);
        short8 k2 = ld8(&lds[KOFF2 + ((eh * 8 + j0 + 2) * 16 + t) * 40 + q * 8]);
        short8 k3 = ld8(&lds[KOFF2 + ((eh * 8 + j0 + 3) * 16 + t) * 40 + q * 8]);
        #pragma unroll
        for (int z = 0; z < 8; ++z) {
          a0 = fmaf(sel8[z], b2f((u16)k0[z]), a0);
          a1 = fmaf(sel8[z], b2f((u16)k1[z]), a1);
          a2 = fmaf(sel8[z], b2f((u16)k2[z]), a2);
          a3 = fmaf(sel8[z], b2f((u16)k3[z]), a3);
        }
      }
      // store 4 logits f32 into spare cols 32..39 (jh=0 -> SOFF2 spare, jh=1 -> KOFF2 spare)
      float4 lg4; lg4.x = a0; lg4.y = a1; lg4.z = a2; lg4.w = a3;
      float4* dst = reinterpret_cast<float4*>(
          &lds[(jh ? KOFF2 : SOFF2) + rit * 40 + 32]);
      *dst = lg4;
    }
    __syncthreads();   // B2: logits visible; val slice staged; keys/sel data dead

    // ---- P5b: softmax (tid<256); w (f32) -> KOFF2 cols 0..15 of row rit ----
    if (tid < 256) {
      const int eh = tid >> 7, i = (tid >> 4) & 7, t = tid & 15;
      const int rit = (eh * 8 + i) * 16 + t;
      float4 l0 = *reinterpret_cast<const float4*>(&lds[SOFF2 + rit * 40 + 32]);
      float4 l1 = *reinterpret_cast<const float4*>(&lds[KOFF2 + rit * 40 + 32]);
      float lgt[NA] = {l0.x, l0.y, l0.z, l0.w, l1.x, l1.y, l1.z, l1.w};
      #pragma unroll
      for (int j = 0; j < NA; ++j)
        lgt[j] = (j == i) ? -1e9f : lgt[j] * 0.17677669529663687f;  // 1/sqrt(32), self-mask
      float m = lgt[0];
      #pragma unroll
      for (int j = 1; j < NA; ++j) m = fmaxf(m, lgt[j]);
      float s = 0.f;
      #pragma unroll
      for (int j = 0; j < NA; ++j) { lgt[j] = __expf(lgt[j] - m); s += lgt[j]; }
      float inv = 1.f / s;
      float4 w0, w1;
      w0.x = lgt[0] * inv; w0.y = lgt[1] * inv; w0.z = lgt[2] * inv; w0.w = lgt[3] * inv;
      w1.x = lgt[4] * inv; w1.y = lgt[5] * inv; w1.z = lgt[6] * inv; w1.w = lgt[7] * inv;
      float4* wd = reinterpret_cast<float4*>(&lds[KOFF2 + rit * 40]);
      wd[0] = w0; wd[1] = w1;
    }

    // ---- P6: vals = lrelu(sa @ valW + valb) -> SOFF2 cols 0..31 (B from LDS/WK2) ----
    #pragma unroll
    for (int ntL = 0; ntL < 4; ++ntL) {
      const int eh = ntL >> 1, ntl = ntL & 1;
      const int d = ntl * 16 + lr;
      const int rl = eh * 32 + d;
      const int n = (2 * ep + eh) * 32 + d;       // global head-dim index
      const int swz = (lr & 7) * 8;
      const u16* wr = &lds[WK2 + rl * 128];
      f32x4 acc = {0.f, 0.f, 0.f, 0.f};
      #pragma unroll
      for (int ks = 0; ks < 4; ++ks) {
        const int col = (ks * 32 + lg * 8) ^ swz;
        acc = __builtin_amdgcn_mfma_f32_16x16x32_bf16(safr[ks], ld8(wr + col), acc, 0, 0, 0);
      }
      float bias = g_valb[n];
      #pragma unroll
      for (int r = 0; r < 4; ++r) {
        const int row = (eh * 8 + a) * 16 + 4 * lg + r;
        lds[SOFF2 + row * 40 + d] = f2b(lrelu(acc[r] + bias));
      }
    }
    __syncthreads();   // B3: vals + w visible

    // ---- P7: other = w @ vals on ALL 512 threads: thread = (qh,eh,i,t), 2 q-blocks ----
    {
      const int qh = tid >> 8, eh = (tid >> 7) & 1, i = (tid >> 4) & 7, t = tid & 15;
      const int rit = (eh * 8 + i) * 16 + t;
      float4 w0 = *reinterpret_cast<const float4*>(&lds[KOFF2 + rit * 40]);
      float4 w1 = *reinterpret_cast<const float4*>(&lds[KOFF2 + rit * 40 + 8]);
      const float wv[NA] = {w0.x, w0.y, w0.z, w0.w, w1.x, w1.y, w1.z, w1.w};
      u16* dst = &g_ci[((size_t)i * BT + g0 + t) * 256 + 128 + (2 * ep + eh) * 32];
      #pragma unroll
      for (int ql = 0; ql < 2; ++ql) {
        const int q = qh * 2 + ql;
        float ov8[8];
        #pragma unroll
        for (int z = 0; z < 8; ++z) ov8[z] = 0.f;
        #pragma unroll
        for (int j = 0; j < NA; ++j) {
          float wj = wv[j];
          short8 v = ld8(&lds[SOFF2 + ((eh * 8 + j) * 16 + t) * 40 + q * 8]);
          #pragma unroll
          for (int z = 0; z < 8; ++z) ov8[z] = fmaf(wj, b2f((u16)v[z]), ov8[z]);
        }
        short8 s;
        #pragma unroll
        for (int z = 0; z < 8; ++z) s[z] = (short)f2b(ov8[z]);
        st8(dst + q * 8, s);
      }
    }
    __syncthreads();   // B4: pass complete; regions reusable
  }
}

// ---------------- K3: h1 = lrelu(ci @ cW1 + cb1); q = (h1 @ cW2 + cb2)[idx] ----------------
__global__ __launch_bounds__(NTHREADS) __attribute__((amdgpu_waves_per_eu(4)))
void maac_crit(const float* __restrict__ g_u, const float* __restrict__ g_cb1,
               const float* __restrict__ g_cb2, float* __restrict__ g_out) {
  __shared__ __align__(16) u16 w1[128 * 264];
  __shared__ __align__(16) u16 scr[5120];
  __shared__ int s_idx[128];

  const int tid = threadIdx.x;
  const int a = blockIdx.y;
  const int tok0 = blockIdx.x * 128;

  if (tid < 128) {
    const float* up = g_u + ((size_t)a * BT + tok0 + tid) * NACT;
    int best = 0; float bv = up[0];
    #pragma unroll
    for (int o = 1; o < NACT; ++o) { float v = up[o]; if (v > bv) { bv = v; best = o; } }
    s_idx[tid] = best;
  }
  for (int z = tid * 8; z < 128 * 256; z += NTHREADS * 8) {
    int n = z >> 8, k = z & 255;
    st8(&w1[n * 264 + k], ld8(&g_wt[OFF_C1 + a * 32768 + n * 256 + k]));
  }
  __syncthreads();

  const int wv = tid >> 6, l = tid & 63, lr = l & 15, lg = l >> 4;
  const int g0 = tok0 + wv * 16;
  const int scrw = wv * 640;

  short8 cf[8];
  #pragma unroll
  for (int ks = 0; ks < 8; ++ks)
    cf[ks] = ld8(&g_ci[((size_t)a * BT + g0 + lr) * 256 + ks * 32 + lg * 8]);

  short8 h1fr[4];
  #pragma unroll
  for (int g = 0; g < 4; ++g) {
    #pragma unroll
    for (int ntl = 0; ntl < 2; ++ntl) {
      const int nt = 2 * g + ntl;
      f32x4 acc = {0.f, 0.f, 0.f, 0.f};
      const u16* wr = &w1[(nt * 16 + lr) * 264 + lg * 8];
      #pragma unroll
      for (int ks = 0; ks < 8; ++ks)
        acc = __builtin_amdgcn_mfma_f32_16x16x32_bf16(cf[ks], ld8(wr + ks * 32), acc, 0, 0, 0);
      float bias = g_cb1[a * NH + nt * 16 + lr];
      #pragma unroll
      for (int r = 0; r < 4; ++r)
        scr[scrw + (4 * lg + r) * 40 + ntl * 16 + lr] = f2b(lrelu(acc[r] + bias));
    }
    h1fr[g] = ld8(&scr[scrw + lr * 40 + lg * 8]);
  }

  {
    f32x4 acc = {0.f, 0.f, 0.f, 0.f};
    const u16* wr = g_wt + OFF_C2 + a * 2048 + lr * 128 + lg * 8;
    #pragma unroll
    for (int ks = 0; ks < 4; ++ks)
      acc = __builtin_amdgcn_mfma_f32_16x16x32_bf16(h1fr[ks], ld8(wr + ks * 32), acc, 0, 0, 0);
    float bias = g_cb2[a * NACT + lr];
    #pragma unroll
    for (int r = 0; r < 4; ++r) {
      int t = 4 * lg + r;
      if ((int)lr == s_idx[wv * 16 + t])
        g_out[(size_t)a * BT + g0 + t] = acc[r] + bias;
    }
  }
}

extern "C" void kernel_launch(void* const* d_in, const int* in_sizes, int n_in,
                              void* d_out, int out_size, void* d_ws, size_t ws_size,
                              hipStream_t stream) {
  (void)in_sizes; (void)n_in; (void)d_ws; (void)ws_size; (void)out_size;
  const float* obs  = (const float*)d_in[0];
  const float* u    = (const float*)d_in[1];
  const float* encW = (const float*)d_in[2];
  const float* encb = (const float*)d_in[3];
  const float* sW   = (const float*)d_in[4];
  const float* sb   = (const float*)d_in[5];
  const float* keyW = (const float*)d_in[6];
  const float* selW = (const float*)d_in[7];
  const float* valW = (const float*)d_in[8];
  const float* valb = (const float*)d_in[9];
  const float* cW1  = (const float*)d_in[10];
  const float* cb1  = (const float*)d_in[11];
  const float* cW2  = (const float*)d_in[12];
  const float* cb2  = (const float*)d_in[13];

  hipLaunchKernelGGL(maac_wt, dim3(1920), dim3(256), 0, stream,
                     encW, sW, keyW, selW, valW, cW1, cW2);
  hipLaunchKernelGGL(maac_enc, dim3(BT / 128, NA), dim3(NTHREADS), 0, stream,
                     obs, u, encb, sb);
  hipLaunchKernelGGL(maac_attn, dim3(BT / TOK), dim3(NTHREADS), 0, stream, valb);
  hipLaunchKernelGGL(maac_crit, dim3(BT / 128, NA), dim3(NTHREADS), 0, stream,
                     u, cb1, cb2, (float*)d_out);
}

// Round 21
// 206.267 us; speedup vs baseline: 1.1166x; 1.1166x over previous
//
#include <hip/hip_runtime.h>

namespace {
constexpr int NA = 8, BT = 32768, NOBS = 64, NACT = 16, NH = 128;
constexpr int TOK = 16, NTHREADS = 512;
// g_wt table offsets (u16 units)
constexpr int OFF_ENC = 0;        // [8][128n][96k] (k>=80 zero)
constexpr int OFF_S   = 98304;    // [8][128n][64k]
constexpr int OFF_KEY = 163840;   // [128n][128k]  n = e*32+d
constexpr int OFF_SEL = 180224;   // [128n][128k]
constexpr int OFF_VAL = 196608;   // [128n][128k]
constexpr int OFF_C1  = 212992;   // [8][128n][256k]
constexpr int OFF_C2  = 475136;   // [8][16n][128k]
constexpr int WT_TOTAL = 491520;
// enc LDS (u16): WENC [128][104] (96 used), WS_ [128][72] (64 used), SCR 8x640
constexpr int WENC = 0, WS_ = 13312, ESCR = 22528, ENC_LDS = 27648;   // 55,296 B
// attn LDS (u16), per-head-pass slices: WK2/WS2 [64n][128] swizzled, KOFF2/SOFF2 [256][40]
constexpr int WK2 = 0, WS2 = 8192, KOFF2 = 16384, SOFF2 = 26624, ATTN_LDS = 36864; // 73,728 B
}

typedef short short8 __attribute__((ext_vector_type(8)));
typedef float f32x4 __attribute__((ext_vector_type(4)));
typedef unsigned short u16;

__device__ u16 g_wt[WT_TOTAL];
__device__ u16 g_sa[(size_t)NA * BT * NH];       // [a][t][128] sa-encodings
__device__ u16 g_ci[(size_t)NA * BT * 2 * NH];   // [a][t][256]: 0-127 se, 128-255 other

__device__ __forceinline__ u16 f2b(float x) {  // RNE f32->bf16
  unsigned b = __float_as_uint(x);
  return (u16)((b + 0x7FFFu + ((b >> 16) & 1u)) >> 16);
}
__device__ __forceinline__ float b2f(u16 h) { return __uint_as_float(((unsigned)h) << 16); }
__device__ __forceinline__ float lrelu(float x) { return x > 0.0f ? x : 0.01f * x; }
__device__ __forceinline__ short8 ld8(const u16* p) { return *reinterpret_cast<const short8*>(p); }
__device__ __forceinline__ void st8(u16* p, short8 v) { *reinterpret_cast<short8*>(p) = v; }
__device__ __forceinline__ short8 pk8(float4 p, float4 q) {
  short8 r;
  r[0] = (short)f2b(p.x); r[1] = (short)f2b(p.y); r[2] = (short)f2b(p.z); r[3] = (short)f2b(p.w);
  r[4] = (short)f2b(q.x); r[5] = (short)f2b(q.y); r[6] = (short)f2b(q.z); r[7] = (short)f2b(q.w);
  return r;
}

// ---------------- K0: transpose+cvt all weights into g_wt ----------------
__global__ void maac_wt(const float* __restrict__ encW, const float* __restrict__ sW,
                        const float* __restrict__ keyW, const float* __restrict__ selW,
                        const float* __restrict__ valW, const float* __restrict__ cW1,
                        const float* __restrict__ cW2) {
  for (int i = blockIdx.x * blockDim.x + threadIdx.x; i < WT_TOTAL; i += gridDim.x * blockDim.x) {
    float v; int o = i;
    if (o < OFF_S) {                // enc: [a][n][96] <- encW[a][k][n], zero k>=80
      int a = o / 12288, r = o % 12288, n = r / 96, k = r % 96;
      v = (k < 80) ? encW[a * 10240 + k * 128 + n] : 0.0f;
    } else if (o < OFF_KEY) {       // s: [a][n][64]
      int q = o - OFF_S; int a = q / 8192, r = q % 8192, n = r / 64, k = r % 64;
      v = sW[a * 8192 + k * 128 + n];
    } else if (o < OFF_SEL) {       // key: [n=e*32+d][k=h]
      int q = o - OFF_KEY; int n = q / 128, k = q % 128;
      v = keyW[(n >> 5) * 4096 + k * 32 + (n & 31)];
    } else if (o < OFF_VAL) {
      int q = o - OFF_SEL; int n = q / 128, k = q % 128;
      v = selW[(n >> 5) * 4096 + k * 32 + (n & 31)];
    } else if (o < OFF_C1) {
      int q = o - OFF_VAL; int n = q / 128, k = q % 128;
      v = valW[(n >> 5) * 4096 + k * 32 + (n & 31)];
    } else if (o < OFF_C2) {        // c1: [a][n][256]
      int q = o - OFF_C1; int a = q / 32768, r = q % 32768, n = r / 256, k = r % 256;
      v = cW1[a * 32768 + k * 128 + n];
    } else {                        // c2: [a][n=o][128]
      int q = o - OFF_C2; int a = q / 2048, r = q % 2048, n = r / 128, k = r % 128;
      v = cW2[a * 2048 + k * 16 + n];
    }
    g_wt[i] = f2b(v);
  }
}

// ---------------- K1: enc + s_enc, crit-pattern: per-agent 128-token blocks ----------------
__global__ __launch_bounds__(NTHREADS) __attribute__((amdgpu_waves_per_eu(4)))
void maac_enc(const float* __restrict__ g_obs, const float* __restrict__ g_u,
              const float* __restrict__ g_encb, const float* __restrict__ g_sb) {
  __shared__ __align__(16) u16 lds[ENC_LDS];

  const int tid = threadIdx.x;
  const int a = blockIdx.y;
  const int tok0 = blockIdx.x * 128;

  // stage encW[a] rows(96) -> 104-pad; sW[a] rows(64) -> 72-pad (both <=2-way banks)
  for (int z = tid * 8; z < 12288; z += NTHREADS * 8) {
    int row = z / 96, k = z - row * 96;
    st8(&lds[WENC + row * 104 + k], ld8(&g_wt[OFF_ENC + a * 12288 + z]));
  }
  for (int z = tid * 8; z < 8192; z += NTHREADS * 8) {
    int row = z >> 6, k = z & 63;
    st8(&lds[WS_ + row * 72 + k], ld8(&g_wt[OFF_S + a * 8192 + z]));
  }
  __syncthreads();

  const int wv = tid >> 6, l = tid & 63, lr = l & 15, lg = l >> 4;
  const int g0 = tok0 + wv * 16;
  const int scrw = ESCR + wv * 640;

  // A-frags: row = token g0+lr, k = ks*32+lg*8+j
  short8 afr0, afr1, afr2;
  {
    const float4* o4 = reinterpret_cast<const float4*>(g_obs + ((size_t)a * BT + g0 + lr) * NOBS);
    afr0 = pk8(o4[lg * 2], o4[lg * 2 + 1]);
    afr1 = pk8(o4[8 + lg * 2], o4[8 + lg * 2 + 1]);
    if (lg < 2) {
      const float4* u4 = reinterpret_cast<const float4*>(g_u + ((size_t)a * BT + g0 + lr) * NACT);
      afr2 = pk8(u4[lg * 2], u4[lg * 2 + 1]);
    } else {
      afr2 = short8{0, 0, 0, 0, 0, 0, 0, 0};
    }
  }

  // P1: sa = lrelu(inp @ encW + encb) -> granule roundtrip -> g_sa
  #pragma unroll
  for (int g = 0; g < 4; ++g) {
    #pragma unroll
    for (int ntl = 0; ntl < 2; ++ntl) {
      const int nt = 2 * g + ntl;
      f32x4 acc = {0.f, 0.f, 0.f, 0.f};
      const u16* wr = &lds[WENC + (nt * 16 + lr) * 104 + lg * 8];
      acc = __builtin_amdgcn_mfma_f32_16x16x32_bf16(afr0, ld8(wr), acc, 0, 0, 0);
      acc = __builtin_amdgcn_mfma_f32_16x16x32_bf16(afr1, ld8(wr + 32), acc, 0, 0, 0);
      acc = __builtin_amdgcn_mfma_f32_16x16x32_bf16(afr2, ld8(wr + 64), acc, 0, 0, 0);
      float bias = g_encb[a * NH + nt * 16 + lr];
      #pragma unroll
      for (int r = 0; r < 4; ++r)
        lds[scrw + (4 * lg + r) * 40 + ntl * 16 + lr] = f2b(lrelu(acc[r] + bias));
    }
    st8(&g_sa[((size_t)a * BT + g0 + lr) * NH + g * 32 + lg * 8],
        ld8(&lds[scrw + lr * 40 + lg * 8]));   // wave-private, DS-ordered
  }
  // P2: se = lrelu(obs @ sW + sb) -> g_ci cols 0..127
  #pragma unroll
  for (int g = 0; g < 4; ++g) {
    #pragma unroll
    for (int ntl = 0; ntl < 2; ++ntl) {
      const int nt = 2 * g + ntl;
      f32x4 acc = {0.f, 0.f, 0.f, 0.f};
      const u16* wr = &lds[WS_ + (nt * 16 + lr) * 72 + lg * 8];
      acc = __builtin_amdgcn_mfma_f32_16x16x32_bf16(afr0, ld8(wr), acc, 0, 0, 0);
      acc = __builtin_amdgcn_mfma_f32_16x16x32_bf16(afr1, ld8(wr + 32), acc, 0, 0, 0);
      float bias = g_sb[a * NH + nt * 16 + lr];
      #pragma unroll
      for (int r = 0; r < 4; ++r)
        lds[scrw + (4 * lg + r) * 40 + ntl * 16 + lr] = f2b(lrelu(acc[r] + bias));
    }
    st8(&g_ci[((size_t)a * BT + g0 + lr) * 256 + g * 32 + lg * 8],
        ld8(&lds[scrw + lr * 40 + lg * 8]));
  }
}

// ---------------- K2: attention, two head-passes + q-blocked P5/P7, ARCH-VGPR<=64 ----------------
// r18 champion verbatim (measured: VGPR 64, occ 41%, attn ~114 us, total 207 us).
// r20's 512-thread P5/P7 split REGRESSED (+60 MB spill: widened per-phase live set past
// the 64-reg cap). Narrow q-blocked phases are the right shape for the 64-reg bank.
__global__ __launch_bounds__(NTHREADS) __attribute__((amdgpu_waves_per_eu(4)))
void maac_attn(const float* __restrict__ g_valb) {
  __shared__ __align__(16) u16 lds[ATTN_LDS];

  const int tid = threadIdx.x;
  const int g0 = blockIdx.x * TOK;
  const int a = tid >> 6, l = tid & 63, lr = l & 15, lg = l >> 4;

  // sa/se fragments from global (one-time)
  short8 safr[4], sefr[4];
  #pragma unroll
  for (int ks = 0; ks < 4; ++ks) {
    safr[ks] = ld8(&g_sa[((size_t)a * BT + g0 + lr) * NH + ks * 32 + lg * 8]);
    sefr[ks] = ld8(&g_ci[((size_t)a * BT + g0 + lr) * 256 + ks * 32 + lg * 8]);
  }

  for (int ep = 0; ep < 2; ++ep) {
    // ---- stage key/sel slices for heads {2ep, 2ep+1}: rows ep*64..+63, col-swizzled ----
    for (int z = tid * 8; z < 8192; z += NTHREADS * 8) {
      int rl = z >> 7, c = z & 127;
      int cs = c ^ ((rl & 7) * 8);
      st8(&lds[WK2 + rl * 128 + cs], ld8(&g_wt[OFF_KEY + ep * 8192 + z]));
      st8(&lds[WS2 + rl * 128 + cs], ld8(&g_wt[OFF_SEL + ep * 8192 + z]));
    }
    __syncthreads();   // B0: slices staged (orders vs prev pass's P7 SOFF2 reads)

    // ---- P3: keys -> KOFF2 ; sel -> SOFF2 (B from LDS, swizzled) ----
    #pragma unroll
    for (int ntL = 0; ntL < 4; ++ntL) {
      const int eh = ntL >> 1, ntl = ntL & 1;
      const int d = ntl * 16 + lr;
      const int rl = eh * 32 + d;                 // local weight row
      const int swz = (lr & 7) * 8;
      const u16* wk = &lds[WK2 + rl * 128];
      const u16* ws = &lds[WS2 + rl * 128];
      f32x4 ak = {0.f, 0.f, 0.f, 0.f}, as_ = {0.f, 0.f, 0.f, 0.f};
      #pragma unroll
      for (int ks = 0; ks < 4; ++ks) {
        const int col = (ks * 32 + lg * 8) ^ swz;
        ak  = __builtin_amdgcn_mfma_f32_16x16x32_bf16(safr[ks], ld8(wk + col), ak, 0, 0, 0);
        as_ = __builtin_amdgcn_mfma_f32_16x16x32_bf16(sefr[ks], ld8(ws + col), as_, 0, 0, 0);
      }
      #pragma unroll
      for (int r = 0; r < 4; ++r) {
        const int row = (eh * 8 + a) * 16 + 4 * lg + r;
        lds[KOFF2 + row * 40 + d] = f2b(ak[r]);
        lds[SOFF2 + row * 40 + d] = f2b(as_[r]);
      }
    }
    __syncthreads();   // B1: keys+sel visible; WK2/WS2 now dead

    // ---- val-slice staging into WK2 (overlaps with P5 below; no region conflict) ----
    for (int z = tid * 8; z < 8192; z += NTHREADS * 8) {
      int rl = z >> 7, c = z & 127;
      int cs = c ^ ((rl & 7) * 8);
      st8(&lds[WK2 + rl * 128 + cs], ld8(&g_wt[OFF_VAL + ep * 8192 + z]));
    }

    // ---- P5: logits + masked softmax (tid<256), q-blocked, w in regs ----
    float w[NA];
    if (tid < 256) {
      const int eh = tid >> 7, i = (tid >> 4) & 7, t = tid & 15;
      float acc[NA];
      #pragma unroll
      for (int j = 0; j < NA; ++j) acc[j] = 0.f;
      #pragma unroll
      for (int q = 0; q < 4; ++q) {
        short8 s = ld8(&lds[SOFF2 + ((eh * 8 + i) * 16 + t) * 40 + q * 8]);
        float sel8[8];
        #pragma unroll
        for (int z = 0; z < 8; ++z) sel8[z] = b2f((u16)s[z]);
        #pragma unroll
        for (int j = 0; j < NA; ++j) {
          short8 k8 = ld8(&lds[KOFF2 + ((eh * 8 + j) * 16 + t) * 40 + q * 8]);
          #pragma unroll
          for (int z = 0; z < 8; ++z) acc[j] = fmaf(sel8[z], b2f((u16)k8[z]), acc[j]);
        }
      }
      #pragma unroll
      for (int j = 0; j < NA; ++j)
        acc[j] = (j == i) ? -1e9f : acc[j] * 0.17677669529663687f;  // 1/sqrt(32), self-mask
      float m = acc[0];
      #pragma unroll
      for (int j = 1; j < NA; ++j) m = fmaxf(m, acc[j]);
      float s = 0.f;
      #pragma unroll
      for (int j = 0; j < NA; ++j) { acc[j] = __expf(acc[j] - m); s += acc[j]; }
      float inv = 1.f / s;
      #pragma unroll
      for (int j = 0; j < NA; ++j) w[j] = acc[j] * inv;
    }
    __syncthreads();   // B2: P5 reads done + val slice staged

    // ---- P6: vals = lrelu(sa @ valW + valb) -> SOFF2 (B from LDS/WK2, swizzled) ----
    #pragma unroll
    for (int ntL = 0; ntL < 4; ++ntL) {
      const int eh = ntL >> 1, ntl = ntL & 1;
      const int d = ntl * 16 + lr;
      const int rl = eh * 32 + d;
      const int n = (2 * ep + eh) * 32 + d;       // global head-dim index
      const int swz = (lr & 7) * 8;
      const u16* wr = &lds[WK2 + rl * 128];
      f32x4 acc = {0.f, 0.f, 0.f, 0.f};
      #pragma unroll
      for (int ks = 0; ks < 4; ++ks) {
        const int col = (ks * 32 + lg * 8) ^ swz;
        acc = __builtin_amdgcn_mfma_f32_16x16x32_bf16(safr[ks], ld8(wr + col), acc, 0, 0, 0);
      }
      float bias = g_valb[n];
      #pragma unroll
      for (int r = 0; r < 4; ++r) {
        const int row = (eh * 8 + a) * 16 + 4 * lg + r;
        lds[SOFF2 + row * 40 + d] = f2b(lrelu(acc[r] + bias));
      }
    }
    __syncthreads();   // B3: vals visible

    // ---- P7: other = w @ vals (tid<256), q-blocked -> g_ci cols 128..255 ----
    if (tid < 256) {
      const int eh = tid >> 7, i = (tid >> 4) & 7, t = tid & 15;
      u16* dst = &g_ci[((size_t)i * BT + g0 + t) * 256 + 128 + (2 * ep + eh) * 32];
      #pragma unroll
      for (int q = 0; q < 4; ++q) {
        float ov8[8];
        #pragma unroll
        for (int z = 0; z < 8; ++z) ov8[z] = 0.f;
        #pragma unroll
        for (int j = 0; j < NA; ++j) {
          float wj = w[j];
          short8 v = ld8(&lds[SOFF2 + ((eh * 8 + j) * 16 + t) * 40 + q * 8]);
          #pragma unroll
          for (int z = 0; z < 8; ++z) ov8[z] = fmaf(wj, b2f((u16)v[z]), ov8[z]);
        }
        short8 s;
        #pragma unroll
        for (int z = 0; z < 8; ++z) s[z] = (short)f2b(ov8[z]);
        st8(dst + q * 8, s);
      }
    }
    __syncthreads();   // B4: pass complete; regions reusable
  }
}

// ---------------- K3: h1 = lrelu(ci @ cW1 + cb1); q = (h1 @ cW2 + cb2)[idx] ----------------
__global__ __launch_bounds__(NTHREADS) __attribute__((amdgpu_waves_per_eu(4)))
void maac_crit(const float* __restrict__ g_u, const float* __restrict__ g_cb1,
               const float* __restrict__ g_cb2, float* __restrict__ g_out) {
  __shared__ __align__(16) u16 w1[128 * 264];
  __shared__ __align__(16) u16 scr[5120];
  __shared__ int s_idx[128];

  const int tid = threadIdx.x;
  const int a = blockIdx.y;
  const int tok0 = blockIdx.x * 128;

  if (tid < 128) {
    const float* up = g_u + ((size_t)a * BT + tok0 + tid) * NACT;
    int best = 0; float bv = up[0];
    #pragma unroll
    for (int o = 1; o < NACT; ++o) { float v = up[o]; if (v > bv) { bv = v; best = o; } }
    s_idx[tid] = best;
  }
  for (int z = tid * 8; z < 128 * 256; z += NTHREADS * 8) {
    int n = z >> 8, k = z & 255;
    st8(&w1[n * 264 + k], ld8(&g_wt[OFF_C1 + a * 32768 + n * 256 + k]));
  }
  __syncthreads();

  const int wv = tid >> 6, l = tid & 63, lr = l & 15, lg = l >> 4;
  const int g0 = tok0 + wv * 16;
  const int scrw = wv * 640;

  short8 cf[8];
  #pragma unroll
  for (int ks = 0; ks < 8; ++ks)
    cf[ks] = ld8(&g_ci[((size_t)a * BT + g0 + lr) * 256 + ks * 32 + lg * 8]);

  short8 h1fr[4];
  #pragma unroll
  for (int g = 0; g < 4; ++g) {
    #pragma unroll
    for (int ntl = 0; ntl < 2; ++ntl) {
      const int nt = 2 * g + ntl;
      f32x4 acc = {0.f, 0.f, 0.f, 0.f};
      const u16* wr = &w1[(nt * 16 + lr) * 264 + lg * 8];
      #pragma unroll
      for (int ks = 0; ks < 8; ++ks)
        acc = __builtin_amdgcn_mfma_f32_16x16x32_bf16(cf[ks], ld8(wr + ks * 32), acc, 0, 0, 0);
      float bias = g_cb1[a * NH + nt * 16 + lr];
      #pragma unroll
      for (int r = 0; r < 4; ++r)
        scr[scrw + (4 * lg + r) * 40 + ntl * 16 + lr] = f2b(lrelu(acc[r] + bias));
    }
    h1fr[g] = ld8(&scr[scrw + lr * 40 + lg * 8]);
  }

  {
    f32x4 acc = {0.f, 0.f, 0.f, 0.f};
    const u16* wr = g_wt + OFF_C2 + a * 2048 + lr * 128 + lg * 8;
    #pragma unroll
    for (int ks = 0; ks < 4; ++ks)
      acc = __builtin_amdgcn_mfma_f32_16x16x32_bf16(h1fr[ks], ld8(wr + ks * 32), acc, 0, 0, 0);
    float bias = g_cb2[a * NACT + lr];
    #pragma unroll
    for (int r = 0; r < 4; ++r) {
      int t = 4 * lg + r;
      if ((int)lr == s_idx[wv * 16 + t])
        g_out[(size_t)a * BT + g0 + t] = acc[r] + bias;
    }
  }
}

extern "C" void kernel_launch(void* const* d_in, const int* in_sizes, int n_in,
                              void* d_out, int out_size, void* d_ws, size_t ws_size,
                              hipStream_t stream) {
  (void)in_sizes; (void)n_in; (void)d_ws; (void)ws_size; (void)out_size;
  const float* obs  = (const float*)d_in[0];
  const float* u    = (const float*)d_in[1];
  const float* encW = (const float*)d_in[2];
  const float* encb = (const float*)d_in[3];
  const float* sW   = (const float*)d_in[4];
  const float* sb   = (const float*)d_in[5];
  const float* keyW = (const float*)d_in[6];
  const float* selW = (const float*)d_in[7];
  const float* valW = (const float*)d_in[8];
  const float* valb = (const float*)d_in[9];
  const float* cW1  = (const float*)d_in[10];
  const float* cb1  = (const float*)d_in[11];
  const float* cW2  = (const float*)d_in[12];
  const float* cb2  = (const float*)d_in[13];

  hipLaunchKernelGGL(maac_wt, dim3(1920), dim3(256), 0, stream,
                     encW, sW, keyW, selW, valW, cW1, cW2);
  hipLaunchKernelGGL(maac_enc, dim3(BT / 128, NA), dim3(NTHREADS), 0, stream,
                     obs, u, encb, sb);
  hipLaunchKernelGGL(maac_attn, dim3(BT / TOK), dim3(NTHREADS), 0, stream, valb);
  hipLaunchKernelGGL(maac_crit, dim3(BT / 128, NA), dim3(NTHREADS), 0, stream,
                     u, cb1, cb2, (float*)d_out);
}